// Round 1
// baseline (63.063 us; speedup 1.0000x reference)
//
#include <hip/hip_runtime.h>

// Problem constants (from reference)
constexpr int COLS    = 8;
constexpr int BATCH   = 8192;
constexpr int D       = 128;
constexpr int NUM_EMB = 12;
constexpr int NPAIRS  = 28;

__device__ __forceinline__ float dot4(const float4 a, const float4 b) {
    return fmaf(a.x, b.x, fmaf(a.y, b.y, fmaf(a.z, b.z, a.w * b.w)));
}

__device__ __forceinline__ float4 ld4(const float* p) {
    return *reinterpret_cast<const float4*>(p);
}

__device__ __forceinline__ float softplus01(float x) {
    // 0.01 * log(1 + exp(x)); inputs ~N(0,1) so expf is safe, guard anyway
    return 0.01f * ((x > 15.0f) ? x : log1pf(expf(x)));
}

// Block = 256 threads = 4 waves; each 32-lane half-wave owns one batch row.
// 8 rows per block -> grid = 8192/8 = 1024 blocks.
__global__ __launch_bounds__(256) void dsnas_kernel(
    const int*   __restrict__ features,   // [COLS, BATCH]
    const float* __restrict__ emb_mean,   // [COLS, NUM_EMB, D]
    const float* __restrict__ emb_std,    // [COLS, NUM_EMB, D]
    const float* __restrict__ W_nc,       // [NPAIRS, 4, 2, D]
    const float* __restrict__ W_cat,      // [NPAIRS, 2, 2*D]
    const float* __restrict__ log_alpha,  // [NPAIRS, 5]
    const float* __restrict__ noise,      // [NPAIRS, 2, BATCH, D]
    float*       __restrict__ out)        // [BATCH, 2]
{
    __shared__ int pos_s[NPAIRS];

    const int tid = threadIdx.x;

    // Per-block: hard top-1 routing per pair (argmax over 5, first-max ties)
    if (tid < NPAIRS) {
        const float* la = log_alpha + tid * 5;
        float best = la[0];
        int   bi   = 0;
        #pragma unroll
        for (int t = 1; t < 5; ++t) {
            float v = la[t];
            if (v > best) { best = v; bi = t; }
        }
        pos_s[tid] = bi;
    }
    __syncthreads();

    const int b    = blockIdx.x * 8 + (tid >> 5);  // one batch row per half-wave
    const int lane = tid & 31;
    const int d0   = lane * 4;                     // 4 consecutive d per lane

    // Precompute per-column mean + 0.01*softplus(std) for this row's 4 dims.
    // Indexed only with compile-time constants after unroll -> stays in VGPRs.
    float4 Mv[COLS], Sv[COLS];
    #pragma unroll
    for (int i = 0; i < COLS; ++i) {
        const int fi = features[i * BATCH + b];
        const float4 m = ld4(emb_mean + ((size_t)(i * NUM_EMB + fi)) * D + d0);
        const float4 s = ld4(emb_std  + ((size_t)(i * NUM_EMB + fi)) * D + d0);
        Mv[i] = m;
        float4 sp;
        sp.x = softplus01(s.x);
        sp.y = softplus01(s.y);
        sp.z = softplus01(s.z);
        sp.w = softplus01(s.w);
        Sv[i] = sp;
    }

    float acc0 = 0.0f, acc1 = 0.0f;

    constexpr int PI[NPAIRS] = {0,0,0,0,0,0,0, 1,1,1,1,1,1, 2,2,2,2,2, 3,3,3,3, 4,4,4, 5,5, 6};
    constexpr int PJ[NPAIRS] = {1,2,3,4,5,6,7, 2,3,4,5,6,7, 3,4,5,6,7, 4,5,6,7, 5,6,7, 6,7, 7};

    #pragma unroll
    for (int k = 0; k < NPAIRS; ++k) {
        const int i = PI[k];
        const int j = PJ[k];

        const float4 n0 = ld4(noise + (((size_t)(k * 2 + 0) * BATCH + b) * D + d0));
        const float4 n1 = ld4(noise + (((size_t)(k * 2 + 1) * BATCH + b) * D + d0));

        float4 p, q;
        p.x = fmaf(Sv[i].x, n0.x, Mv[i].x);
        p.y = fmaf(Sv[i].y, n0.y, Mv[i].y);
        p.z = fmaf(Sv[i].z, n0.z, Mv[i].z);
        p.w = fmaf(Sv[i].w, n0.w, Mv[i].w);
        q.x = fmaf(Sv[j].x, n1.x, Mv[j].x);
        q.y = fmaf(Sv[j].y, n1.y, Mv[j].y);
        q.z = fmaf(Sv[j].z, n1.z, Mv[j].z);
        q.w = fmaf(Sv[j].w, n1.w, Mv[j].w);

        const int s = __builtin_amdgcn_readfirstlane(pos_s[k]);  // wave-uniform branch

        if (s == 4) {
            // concat branch: p @ Wcat[:, :D] + q @ Wcat[:, D:]
            const float* w0 = W_cat + (size_t)(k * 2 + 0) * (2 * D);
            const float* w1 = W_cat + (size_t)(k * 2 + 1) * (2 * D);
            const float4 a0 = ld4(w0 + d0),     b0 = ld4(w0 + D + d0);
            const float4 a1 = ld4(w1 + d0),     b1 = ld4(w1 + D + d0);
            acc0 += dot4(p, a0) + dot4(q, b0);
            acc1 += dot4(p, a1) + dot4(q, b1);
        } else {
            float4 c;
            if (s == 0) {
                c.x = p.x + q.x; c.y = p.y + q.y; c.z = p.z + q.z; c.w = p.w + q.w;
            } else if (s == 1) {
                c.x = p.x * q.x; c.y = p.y * q.y; c.z = p.z * q.z; c.w = p.w * q.w;
            } else if (s == 2) {
                c.x = fmaxf(p.x, q.x); c.y = fmaxf(p.y, q.y);
                c.z = fmaxf(p.z, q.z); c.w = fmaxf(p.w, q.w);
            } else {
                c.x = fminf(p.x, q.x); c.y = fminf(p.y, q.y);
                c.z = fminf(p.z, q.z); c.w = fminf(p.w, q.w);
            }
            const float* wb = W_nc + ((size_t)(k * 4 + s) * 2) * D;
            const float4 w0 = ld4(wb + d0);      // output 0 row
            const float4 w1 = ld4(wb + D + d0);  // output 1 row
            acc0 += dot4(c, w0);
            acc1 += dot4(c, w1);
        }
    }

    // Reduce across the 32 lanes of this half-wave (xor masks stay in-half)
    #pragma unroll
    for (int m = 16; m >= 1; m >>= 1) {
        acc0 += __shfl_xor(acc0, m, 64);
        acc1 += __shfl_xor(acc1, m, 64);
    }

    if (lane == 0) {
        out[b * 2 + 0] = acc0;
        out[b * 2 + 1] = acc1;
    }
}

extern "C" void kernel_launch(void* const* d_in, const int* in_sizes, int n_in,
                              void* d_out, int out_size, void* d_ws, size_t ws_size,
                              hipStream_t stream) {
    const int*   features  = (const int*)  d_in[0];
    const float* emb_mean  = (const float*)d_in[1];
    const float* emb_std   = (const float*)d_in[2];
    const float* W_nc      = (const float*)d_in[3];
    const float* W_cat     = (const float*)d_in[4];
    const float* log_alpha = (const float*)d_in[5];
    const float* noise     = (const float*)d_in[6];
    float*       out       = (float*)d_out;

    dim3 grid(BATCH / 8);   // 1024 blocks
    dim3 block(256);        // 4 waves, 8 batch rows/block
    dsnas_kernel<<<grid, block, 0, stream>>>(features, emb_mean, emb_std,
                                             W_nc, W_cat, log_alpha, noise, out);
}

// Round 2
// 58.006 us; speedup vs baseline: 1.0872x; 1.0872x over previous
//
#include <hip/hip_runtime.h>

// Problem constants (from reference)
constexpr int COLS    = 8;
constexpr int BATCH   = 8192;
constexpr int D       = 128;
constexpr int NUM_EMB = 12;
constexpr int NPAIRS  = 28;

__device__ __forceinline__ float dot4(const float4 a, const float4 b) {
    return fmaf(a.x, b.x, fmaf(a.y, b.y, fmaf(a.z, b.z, a.w * b.w)));
}

__device__ __forceinline__ float4 ld4(const float* p) {
    return *reinterpret_cast<const float4*>(p);
}

__device__ __forceinline__ float softplus01(float x) {
    // 0.01 * log(1 + exp(x))
    return 0.01f * ((x > 15.0f) ? x : log1pf(expf(x)));
}

// Block = 256 threads = 4 waves; each 32-lane half-wave owns one batch row.
// __launch_bounds__(256, 4): 4 waves/EU = 16 waves/CU -> VGPR capped at 128.
__global__ __launch_bounds__(256, 4) void dsnas_kernel(
    const int*   __restrict__ features,   // [COLS, BATCH]
    const float* __restrict__ emb_mean,   // [COLS, NUM_EMB, D]
    const float* __restrict__ emb_std,    // [COLS, NUM_EMB, D]
    const float* __restrict__ W_nc,       // [NPAIRS, 4, 2, D]
    const float* __restrict__ W_cat,      // [NPAIRS, 2, 2*D]
    const float* __restrict__ log_alpha,  // [NPAIRS, 5]
    const float* __restrict__ noise,      // [NPAIRS, 2, BATCH, D]
    float*       __restrict__ out)        // [BATCH, 2]
{
    __shared__ int pos_s[NPAIRS];

    const int tid = threadIdx.x;

    // Per-block: hard top-1 routing per pair (argmax over 5, first-max wins)
    if (tid < NPAIRS) {
        const float* la = log_alpha + tid * 5;
        float best = la[0];
        int   bi   = 0;
        #pragma unroll
        for (int t = 1; t < 5; ++t) {
            float v = la[t];
            if (v > best) { best = v; bi = t; }
        }
        pos_s[tid] = bi;
    }
    __syncthreads();

    const int b    = blockIdx.x * 8 + (tid >> 5);  // one batch row per half-wave
    const int lane = tid & 31;
    const int d0   = lane * 4;                     // 4 consecutive d per lane

    // Per-column mean + 0.01*softplus(std) for this row's 4 dims, in VGPRs.
    // Indexed only with compile-time constants after unroll (no scratch).
    float4 Mv[COLS], Sv[COLS];
    #pragma unroll
    for (int i = 0; i < COLS; ++i) {
        const int fi = features[i * BATCH + b];
        const float4 m = ld4(emb_mean + ((size_t)(i * NUM_EMB + fi)) * D + d0);
        const float4 s = ld4(emb_std  + ((size_t)(i * NUM_EMB + fi)) * D + d0);
        Mv[i] = m;
        float4 sp;
        sp.x = softplus01(s.x);
        sp.y = softplus01(s.y);
        sp.z = softplus01(s.z);
        sp.w = softplus01(s.w);
        Sv[i] = sp;
    }

    constexpr int PI[NPAIRS] = {0,0,0,0,0,0,0, 1,1,1,1,1,1, 2,2,2,2,2, 3,3,3,3, 4,4,4, 5,5, 6};
    constexpr int PJ[NPAIRS] = {1,2,3,4,5,6,7, 2,3,4,5,6,7, 3,4,5,6,7, 4,5,6,7, 5,6,7, 6,7, 7};

    // Base pointer for this row's noise slice; per-k offsets are 32-bit-safe.
    const float* nrow = noise + (size_t)b * D + d0;
    constexpr size_t KSTRIDE = (size_t)2 * BATCH * D;  // between k's
    constexpr size_t HSTRIDE = (size_t)BATCH * D;      // between halves

    // Depth-1 explicit double buffer (static buf index -> stays in VGPRs).
    float4 nb0[2], nb1[2];
    nb0[0] = ld4(nrow + 0 * KSTRIDE);
    nb1[0] = ld4(nrow + 0 * KSTRIDE + HSTRIDE);

    float acc0 = 0.0f, acc1 = 0.0f;

    #pragma unroll
    for (int k = 0; k < NPAIRS; ++k) {
        const int buf = k & 1;
        const int nxt = buf ^ 1;

        // Prefetch pair k+1's noise BEFORE consuming pair k (issue-early).
        if (k + 1 < NPAIRS) {
            nb0[nxt] = ld4(nrow + (size_t)(k + 1) * KSTRIDE);
            nb1[nxt] = ld4(nrow + (size_t)(k + 1) * KSTRIDE + HSTRIDE);
        }

        const int i = PI[k];
        const int j = PJ[k];
        const float4 n0 = nb0[buf];
        const float4 n1 = nb1[buf];

        float4 p, q;
        p.x = fmaf(Sv[i].x, n0.x, Mv[i].x);
        p.y = fmaf(Sv[i].y, n0.y, Mv[i].y);
        p.z = fmaf(Sv[i].z, n0.z, Mv[i].z);
        p.w = fmaf(Sv[i].w, n0.w, Mv[i].w);
        q.x = fmaf(Sv[j].x, n1.x, Mv[j].x);
        q.y = fmaf(Sv[j].y, n1.y, Mv[j].y);
        q.z = fmaf(Sv[j].z, n1.z, Mv[j].z);
        q.w = fmaf(Sv[j].w, n1.w, Mv[j].w);

        const int s = __builtin_amdgcn_readfirstlane(pos_s[k]);  // wave-uniform

        if (s == 4) {
            // concat branch: p @ Wcat[:, :D] + q @ Wcat[:, D:]
            const float* w0 = W_cat + (size_t)(k * 2 + 0) * (2 * D);
            const float* w1 = W_cat + (size_t)(k * 2 + 1) * (2 * D);
            const float4 a0 = ld4(w0 + d0),     b0 = ld4(w0 + D + d0);
            const float4 a1 = ld4(w1 + d0),     b1 = ld4(w1 + D + d0);
            acc0 += dot4(p, a0) + dot4(q, b0);
            acc1 += dot4(p, a1) + dot4(q, b1);
        } else {
            float4 c;
            if (s == 0) {
                c.x = p.x + q.x; c.y = p.y + q.y; c.z = p.z + q.z; c.w = p.w + q.w;
            } else if (s == 1) {
                c.x = p.x * q.x; c.y = p.y * q.y; c.z = p.z * q.z; c.w = p.w * q.w;
            } else if (s == 2) {
                c.x = fmaxf(p.x, q.x); c.y = fmaxf(p.y, q.y);
                c.z = fmaxf(p.z, q.z); c.w = fmaxf(p.w, q.w);
            } else {
                c.x = fminf(p.x, q.x); c.y = fminf(p.y, q.y);
                c.z = fminf(p.z, q.z); c.w = fminf(p.w, q.w);
            }
            const float* wb = W_nc + ((size_t)(k * 4 + s) * 2) * D;
            const float4 w0 = ld4(wb + d0);      // output-0 row
            const float4 w1 = ld4(wb + D + d0);  // output-1 row
            acc0 += dot4(c, w0);
            acc1 += dot4(c, w1);
        }
    }

    // Reduce across the 32 lanes of this half-wave (xor masks stay in-half)
    #pragma unroll
    for (int m = 16; m >= 1; m >>= 1) {
        acc0 += __shfl_xor(acc0, m, 64);
        acc1 += __shfl_xor(acc1, m, 64);
    }

    if (lane == 0) {
        out[b * 2 + 0] = acc0;
        out[b * 2 + 1] = acc1;
    }
}

extern "C" void kernel_launch(void* const* d_in, const int* in_sizes, int n_in,
                              void* d_out, int out_size, void* d_ws, size_t ws_size,
                              hipStream_t stream) {
    const int*   features  = (const int*)  d_in[0];
    const float* emb_mean  = (const float*)d_in[1];
    const float* emb_std   = (const float*)d_in[2];
    const float* W_nc      = (const float*)d_in[3];
    const float* W_cat     = (const float*)d_in[4];
    const float* log_alpha = (const float*)d_in[5];
    const float* noise     = (const float*)d_in[6];
    float*       out       = (float*)d_out;

    dim3 grid(BATCH / 8);   // 1024 blocks
    dim3 block(256);        // 4 waves, 8 batch rows/block
    dsnas_kernel<<<grid, block, 0, stream>>>(features, emb_mean, emb_std,
                                             W_nc, W_cat, log_alpha, noise, out);
}